// Round 5
// baseline (1095.557 us; speedup 1.0000x reference)
//
#include <hip/hip_runtime.h>
#include <hip/hip_bf16.h>
#include <stdint.h>
#include <string.h>

typedef __bf16 bf16x8 __attribute__((ext_vector_type(8)));
typedef float  f32x4  __attribute__((ext_vector_type(4)));

#define IDX_MASK 131071ull   // 17 bits; requires num_rows <= 131072 (100k here)

// Convert 8 consecutive fp32 (two float4s) to packed bf16x8 (RNE).
static __device__ inline bf16x8 cvt8(const float4 a, const float4 b) {
    bf16x8 r;
    r[0] = (__bf16)a.x; r[1] = (__bf16)a.y; r[2] = (__bf16)a.z; r[3] = (__bf16)a.w;
    r[4] = (__bf16)b.x; r[5] = (__bf16)b.y; r[6] = (__bf16)b.z; r[7] = (__bf16)b.w;
    return r;
}

// ============ pass 1 (x2): U = z @ W1part^T (+bias), bf16 out ============
// wave handles 16 table rows, K=64, N=64: 2 K-steps x 4 N-tiles of
// mfma_f32_16x16x32_bf16. koff selects W1 columns (0 for user, 64 for book).
// Dispatch with zeroCtr=1 also zeroes the bin counters region.
__global__ __launch_bounds__(256, 4)
void precompute_uv(const float* __restrict__ z, const float* __restrict__ w1,
                   const float* __restrict__ bias,      // may be null
                   __hip_bfloat16* __restrict__ Ub,     // [nrows][64] bf16
                   int* __restrict__ ctrs, const int zeroCtr,
                   const int nrows, const int koff)
{
    const int tid = blockIdx.x * blockDim.x + threadIdx.x;
    if (zeroCtr && blockIdx.x == 0 && threadIdx.x < 136)
        ctrs[threadIdx.x] = 0;                // binCount[128] + qCtr[8]

    const int lane = threadIdx.x & 63;
    const int m    = lane & 15;
    const int quad = lane >> 4;

    // B-fragments (hoisted, 32 VGPRs): B[t][s][j] = W1[n=t*16+m][koff+s*32+quad*8+j]
    bf16x8 Bf[4][2];
#pragma unroll
    for (int t = 0; t < 4; ++t) {
        const float* wrow = w1 + (size_t)(t * 16 + m) * 128 + koff;
#pragma unroll
        for (int s = 0; s < 2; ++s) {
            const float4* p = (const float4*)(wrow + s * 32 + quad * 8);
            Bf[t][s] = cvt8(p[0], p[1]);
        }
    }
    float bv[4];
#pragma unroll
    for (int t = 0; t < 4; ++t) bv[t] = bias ? bias[t * 16 + m] : 0.f;

    const int gwave  = (blockIdx.x * blockDim.x + threadIdx.x) >> 6;
    const int nwaves = (gridDim.x * blockDim.x) >> 6;
    const int ngroups = (nrows + 15) >> 4;
    (void)tid;

    for (int g = gwave; g < ngroups; g += nwaves) {
        const int i0 = g << 4;
        int row = i0 + m; if (row >= nrows) row = nrows - 1;
        const float* zrow = z + (size_t)row * 64;
        bf16x8 A[2];
#pragma unroll
        for (int s = 0; s < 2; ++s) {
            const float4* p = (const float4*)(zrow + s * 32 + quad * 8);
            A[s] = cvt8(p[0], p[1]);
        }
        f32x4 acc[4];
#pragma unroll
        for (int t = 0; t < 4; ++t) acc[t] = (f32x4){0.f, 0.f, 0.f, 0.f};
#pragma unroll
        for (int t = 0; t < 4; ++t) {
            acc[t] = __builtin_amdgcn_mfma_f32_16x16x32_bf16(A[0], Bf[t][0], acc[t], 0, 0, 0);
            acc[t] = __builtin_amdgcn_mfma_f32_16x16x32_bf16(A[1], Bf[t][1], acc[t], 0, 0, 0);
        }
        // C layout: reg rr = D[row=quad*4+rr][col=m] of tile t -> col t*16+m
#pragma unroll
        for (int t = 0; t < 4; ++t)
#pragma unroll
            for (int rr = 0; rr < 4; ++rr) {
                const int orow = i0 + quad * 4 + rr;
                if (orow < nrows)
                    Ub[(size_t)orow * 64 + t * 16 + m] =
                        __float2bfloat16(acc[t][rr] + bv[t]);
            }
    }
}

// ============ pass 2: per-bin histogram ============
// bin = ubucket(r)*16 + bbucket(c); buckets via float scale (consistency only).
__global__ __launch_bounds__(256)
void count_bins(const int* __restrict__ eidx, int* __restrict__ binCount,
                const int nedges, const float su, const float sb)
{
    __shared__ int h[128];
    if (threadIdx.x < 128) h[threadIdx.x] = 0;
    __syncthreads();
    const int stride = gridDim.x * blockDim.x;
    for (int e = blockIdx.x * blockDim.x + threadIdx.x; e < nedges; e += stride) {
        const int r = eidx[e], c = eidx[nedges + e];
        int ub = (int)((float)r * su); if (ub > 7)  ub = 7;
        int vb = (int)((float)c * sb); if (vb > 15) vb = 15;
        atomicAdd(&h[ub * 16 + vb], 1);
    }
    __syncthreads();
    if (threadIdx.x < 128 && h[threadIdx.x])
        atomicAdd(&binCount[threadIdx.x], h[threadIdx.x]);
}

// ============ pass 3: serial scan (1 block) ============
__global__ void scan_bins(const int* __restrict__ binCount,
                          int* __restrict__ binStart, int* __restrict__ gCursor)
{
    if (threadIdx.x == 0 && blockIdx.x == 0) {
        int s = 0;
        for (int b = 0; b < 128; ++b) {
            binStart[b] = s; gCursor[b] = s; s += binCount[b];
        }
        binStart[128] = s;
    }
}

// ============ pass 4: scatter edges into bins (packed r|c|eid) ============
__global__ __launch_bounds__(256)
void scatter_bins(const int* __restrict__ eidx, int* __restrict__ gCursor,
                  unsigned long long* __restrict__ pk,
                  const int nedges, const float su, const float sb)
{
    __shared__ int h[128];
    const int chunk = (nedges + gridDim.x - 1) / gridDim.x;
    const int lo = blockIdx.x * chunk;
    const int hi = min(lo + chunk, nedges);

    if (threadIdx.x < 128) h[threadIdx.x] = 0;
    __syncthreads();
    for (int e = lo + threadIdx.x; e < hi; e += blockDim.x) {
        const int r = eidx[e], c = eidx[nedges + e];
        int ub = (int)((float)r * su); if (ub > 7)  ub = 7;
        int vb = (int)((float)c * sb); if (vb > 15) vb = 15;
        atomicAdd(&h[ub * 16 + vb], 1);
    }
    __syncthreads();
    int base = 0, cnt = 0;
    if (threadIdx.x < 128) {
        cnt = h[threadIdx.x];
        if (cnt) base = atomicAdd(&gCursor[threadIdx.x], cnt);
    }
    __syncthreads();
    if (threadIdx.x < 128) h[threadIdx.x] = base;
    __syncthreads();
    for (int e = lo + threadIdx.x; e < hi; e += blockDim.x) {
        const int r = eidx[e], c = eidx[nedges + e];
        int ub = (int)((float)r * su); if (ub > 7)  ub = 7;
        int vb = (int)((float)c * sb); if (vb > 15) vb = 15;
        const int slot = atomicAdd(&h[ub * 16 + vb], 1);
        pk[slot] = (unsigned long long)(unsigned)r
                 | ((unsigned long long)(unsigned)c << 17)
                 | ((unsigned long long)(unsigned)e  << 34);
    }
}

// ============ pass 5: binned edge decode (per-lane, no MFMA) ============
// Queue q = user-bucket q = bins [q*16,(q+1)*16) = contiguous pk range.
// Blocks work-steal 256-edge chunks from the queue matching their PHYSICAL
// XCD (s_getreg HW_REG_XCC_ID, m09-verified) so each XCD's L2 only holds its
// 1.6 MB U-slice + the current 0.8 MB V-slice (bins ordered by book bucket).
// Falls through to other queues afterwards -> correctness is mapping-agnostic.
__global__ __launch_bounds__(256, 4)
void edge_decode_binned(const uint4* __restrict__ Ub, const uint4* __restrict__ Vb,
                        const unsigned long long* __restrict__ pk,
                        const int* __restrict__ binStart, int* __restrict__ qCtr,
                        const float* __restrict__ w2, const float* __restrict__ b2,
                        float* __restrict__ out)
{
    const int lane = threadIdx.x & 63;

    // W2 -> bf16 fragments (16 VGPRs); b2 scalar. (fp32->bf16 of W2 adds
    // ~2^-9 rel err on the layer-2 weights — within budget.)
    bf16x8 W2f[8];
    const float4* w2f4 = (const float4*)w2;
#pragma unroll
    for (int j = 0; j < 8; ++j) W2f[j] = cvt8(w2f4[2 * j], w2f4[2 * j + 1]);
    const float b2f = b2[0];

    const int xcd = __builtin_amdgcn_s_getreg((3 << 11) | (0 << 6) | 20) & 7;

    for (int q = 0; q < 8; ++q) {
        const int qq  = (xcd + q) & 7;
        const int lo  = binStart[qq * 16];
        const int hi  = binStart[qq * 16 + 16];
        const int len = hi - lo;
        if (len <= 0) continue;
        while (true) {
            int t0 = 0;
            if (lane == 0) t0 = atomicAdd(&qCtr[qq], 256);
            t0 = __shfl(t0, 0, 64);
            if (t0 >= len) break;
#pragma unroll
            for (int rep = 0; rep < 4; ++rep) {
                const int e = lo + t0 + rep * 64 + lane;
                if (e >= hi) break;
                const unsigned long long v = pk[e];
                const int r  = (int)(v & IDX_MASK);
                const int c  = (int)((v >> 17) & IDX_MASK);
                const int id = (int)(v >> 34);
                const uint4* up = Ub + (size_t)r * 8;
                const uint4* vp = Vb + (size_t)c * 8;
                float a0 = 0.f, a1 = 0.f, a2 = 0.f, a3 = 0.f;
#pragma unroll
                for (int j = 0; j < 8; ++j) {
                    const bf16x8 u = __builtin_bit_cast(bf16x8, up[j]);
                    const bf16x8 w = __builtin_bit_cast(bf16x8, vp[j]);
                    const bf16x8 t = W2f[j];
                    a0 = fmaf(fmaxf((float)u[0] + (float)w[0], 0.f), (float)t[0], a0);
                    a1 = fmaf(fmaxf((float)u[1] + (float)w[1], 0.f), (float)t[1], a1);
                    a2 = fmaf(fmaxf((float)u[2] + (float)w[2], 0.f), (float)t[2], a2);
                    a3 = fmaf(fmaxf((float)u[3] + (float)w[3], 0.f), (float)t[3], a3);
                    a0 = fmaf(fmaxf((float)u[4] + (float)w[4], 0.f), (float)t[4], a0);
                    a1 = fmaf(fmaxf((float)u[5] + (float)w[5], 0.f), (float)t[5], a1);
                    a2 = fmaf(fmaxf((float)u[6] + (float)w[6], 0.f), (float)t[6], a2);
                    a3 = fmaf(fmaxf((float)u[7] + (float)w[7], 0.f), (float)t[7], a3);
                }
                out[id] = (a0 + a1) + (a2 + a3) + b2f;
            }
        }
    }
}

// ================= fallback A (R4): bf16 gather + MFMA, W1 in LDS =========
__global__ __launch_bounds__(256)
void cvt_bf16_pass(const float* __restrict__ zu, const float* __restrict__ zb,
                   const float* __restrict__ w1,
                   uint4* __restrict__ zub, uint4* __restrict__ zbb,
                   uint4* __restrict__ w1f,
                   const int ngu, const int ngb)
{
    const int stride = gridDim.x * blockDim.x;
    const int tid = blockIdx.x * blockDim.x + threadIdx.x;
    for (int i = tid; i < ngu; i += stride) {
        const float4* s = (const float4*)zu + 2 * (size_t)i;
        zub[i] = __builtin_bit_cast(uint4, cvt8(s[0], s[1]));
    }
    for (int i = tid; i < ngb; i += stride) {
        const float4* s = (const float4*)zb + 2 * (size_t)i;
        zbb[i] = __builtin_bit_cast(uint4, cvt8(s[0], s[1]));
    }
    if (tid < 1024) {
        const int fid = tid >> 6, lane = tid & 63;
        const int t = fid >> 2, s = fid & 3;
        const int n  = t * 16 + (lane & 15);
        const int k0 = s * 32 + (lane >> 4) * 8;
        const float4* src = (const float4*)(w1 + (size_t)n * 128 + k0);
        w1f[tid] = __builtin_bit_cast(uint4, cvt8(src[0], src[1]));
    }
}

__global__ __launch_bounds__(256, 6)
void edge_decoder_mfma_bf16(const uint4* __restrict__ zub, const uint4* __restrict__ zbb,
                            const int* __restrict__ eidx, const uint4* __restrict__ w1f,
                            const float* __restrict__ b1, const float* __restrict__ w2,
                            const float* __restrict__ b2, float* __restrict__ out,
                            const int nedges)
{
    __shared__ uint4 w1lds[16 * 64];
    const int lane = threadIdx.x & 63;
    const int m = lane & 15, quad = lane >> 4;
#pragma unroll
    for (int i = 0; i < 4; ++i)
        w1lds[i * 256 + threadIdx.x] = w1f[i * 256 + threadIdx.x];
    __syncthreads();
    float w2v[4], b1v[4];
#pragma unroll
    for (int t = 0; t < 4; ++t) { w2v[t] = w2[t * 16 + m]; b1v[t] = b1[t * 16 + m]; }
    const float b2f = b2[0];
    const int wavesPerBlock = blockDim.x >> 6;
    const int gwave  = blockIdx.x * wavesPerBlock + (threadIdx.x >> 6);
    const int nwaves = gridDim.x * wavesPerBlock;
    const int* rowp = eidx; const int* colp = eidx + nedges;
    const int ngroups = (nedges + 15) >> 4;
    const uint4* lfrag = w1lds + lane;
    for (int g = gwave; g < ngroups; g += nwaves) {
        const int ebase = g << 4;
        int e = ebase + m; if (e >= nedges) e = nedges - 1;
        const int r = rowp[e], c = colp[e];
        const uint4* up = zub + (size_t)r * 8;
        const uint4* vp = zbb + (size_t)c * 8;
        bf16x8 A[4];
        A[0] = __builtin_bit_cast(bf16x8, up[quad]);
        A[1] = __builtin_bit_cast(bf16x8, up[quad + 4]);
        A[2] = __builtin_bit_cast(bf16x8, vp[quad]);
        A[3] = __builtin_bit_cast(bf16x8, vp[quad + 4]);
        f32x4 acc[4];
#pragma unroll
        for (int t = 0; t < 4; ++t) acc[t] = (f32x4){0.f, 0.f, 0.f, 0.f};
#pragma unroll
        for (int t = 0; t < 4; ++t)
#pragma unroll
            for (int s = 0; s < 4; ++s) {
                bf16x8 B = __builtin_bit_cast(bf16x8, lfrag[(t * 4 + s) * 64]);
                acc[t] = __builtin_amdgcn_mfma_f32_16x16x32_bf16(A[s], B, acc[t], 0, 0, 0);
            }
        float p[4] = {0.f, 0.f, 0.f, 0.f};
#pragma unroll
        for (int t = 0; t < 4; ++t)
#pragma unroll
            for (int rr = 0; rr < 4; ++rr) {
                float h = fmaxf(acc[t][rr] + b1v[t], 0.f);
                p[rr] = fmaf(h, w2v[t], p[rr]);
            }
#pragma unroll
        for (int off = 8; off >= 1; off >>= 1)
#pragma unroll
            for (int rr = 0; rr < 4; ++rr) p[rr] += __shfl_xor(p[rr], off, 64);
        if (m == 0) {
            const int eo = ebase + quad * 4;
            if (eo + 3 < nedges) {
                float4 o; o.x = p[0] + b2f; o.y = p[1] + b2f;
                o.z = p[2] + b2f; o.w = p[3] + b2f;
                *(float4*)(out + eo) = o;
            } else {
#pragma unroll
                for (int rr = 0; rr < 4; ++rr)
                    if (eo + rr < nedges) out[eo + rr] = p[rr] + b2f;
            }
        }
    }
}

// ================= fallback B: direct fp32 gather (no workspace) ==========
__global__ __launch_bounds__(256, 4)
void edge_decoder_mfma_f32(const float* __restrict__ zu, const float* __restrict__ zb,
                           const int* __restrict__ eidx, const float* __restrict__ w1,
                           const float* __restrict__ b1, const float* __restrict__ w2,
                           const float* __restrict__ b2, float* __restrict__ out,
                           const int nedges)
{
    const int lane = threadIdx.x & 63;
    const int m = lane & 15, quad = lane >> 4;
    const int wavesPerBlock = blockDim.x >> 6;
    const int gwave  = blockIdx.x * wavesPerBlock + (threadIdx.x >> 6);
    const int nwaves = gridDim.x * wavesPerBlock;
    bf16x8 Bf[4][4];
#pragma unroll
    for (int t = 0; t < 4; ++t) {
        const float4* wrow = (const float4*)(w1 + (size_t)(t * 16 + m) * 128);
#pragma unroll
        for (int s = 0; s < 4; ++s) {
            const int c0 = s * 8 + quad * 2;
            Bf[t][s] = cvt8(wrow[c0], wrow[c0 + 1]);
        }
    }
    float w2v[4], b1v[4];
#pragma unroll
    for (int t = 0; t < 4; ++t) { w2v[t] = w2[t * 16 + m]; b1v[t] = b1[t * 16 + m]; }
    const float b2f = b2[0];
    const int* rowp = eidx; const int* colp = eidx + nedges;
    const int ngroups = (nedges + 15) >> 4;
    for (int g = gwave; g < ngroups; g += nwaves) {
        const int ebase = g << 4;
        int e = ebase + m; if (e >= nedges) e = nedges - 1;
        const int r = rowp[e], c = colp[e];
        const float4* up = (const float4*)(zu + (size_t)r * 64);
        const float4* vp = (const float4*)(zb + (size_t)c * 64);
        bf16x8 A0 = cvt8(up[quad * 2],     up[quad * 2 + 1]);
        bf16x8 A1 = cvt8(up[8 + quad * 2], up[9 + quad * 2]);
        bf16x8 A2 = cvt8(vp[quad * 2],     vp[quad * 2 + 1]);
        bf16x8 A3 = cvt8(vp[8 + quad * 2], vp[9 + quad * 2]);
        f32x4 acc[4];
#pragma unroll
        for (int t = 0; t < 4; ++t) acc[t] = (f32x4){0.f, 0.f, 0.f, 0.f};
#pragma unroll
        for (int t = 0; t < 4; ++t) {
            acc[t] = __builtin_amdgcn_mfma_f32_16x16x32_bf16(A0, Bf[t][0], acc[t], 0, 0, 0);
            acc[t] = __builtin_amdgcn_mfma_f32_16x16x32_bf16(A1, Bf[t][1], acc[t], 0, 0, 0);
            acc[t] = __builtin_amdgcn_mfma_f32_16x16x32_bf16(A2, Bf[t][2], acc[t], 0, 0, 0);
            acc[t] = __builtin_amdgcn_mfma_f32_16x16x32_bf16(A3, Bf[t][3], acc[t], 0, 0, 0);
        }
        float p[4] = {0.f, 0.f, 0.f, 0.f};
#pragma unroll
        for (int t = 0; t < 4; ++t)
#pragma unroll
            for (int rr = 0; rr < 4; ++rr) {
                float h = fmaxf(acc[t][rr] + b1v[t], 0.f);
                p[rr] = fmaf(h, w2v[t], p[rr]);
            }
#pragma unroll
        for (int off = 8; off >= 1; off >>= 1)
#pragma unroll
            for (int rr = 0; rr < 4; ++rr) p[rr] += __shfl_xor(p[rr], off, 64);
        if (m == 0) {
            const int eo = ebase + quad * 4;
            if (eo + 3 < nedges) {
                float4 o; o.x = p[0] + b2f; o.y = p[1] + b2f;
                o.z = p[2] + b2f; o.w = p[3] + b2f;
                *(float4*)(out + eo) = o;
            } else {
#pragma unroll
                for (int rr = 0; rr < 4; ++rr)
                    if (eo + rr < nedges) out[eo + rr] = p[rr] + b2f;
            }
        }
    }
}

extern "C" void kernel_launch(void* const* d_in, const int* in_sizes, int n_in,
                              void* d_out, int out_size, void* d_ws, size_t ws_size,
                              hipStream_t stream) {
    const float* zu = (const float*)d_in[0];
    const float* zb = (const float*)d_in[1];
    const int*   ei = (const int*)d_in[2];
    const float* w1 = (const float*)d_in[3];
    const float* b1 = (const float*)d_in[4];
    const float* w2 = (const float*)d_in[5];
    const float* b2 = (const float*)d_in[6];
    float* out = (float*)d_out;

    const int nedges = in_sizes[2] / 2;     // edge_label_index is [2, E]
    const int nzu = in_sizes[0], nzb = in_sizes[1];
    const int nU = nzu / 64, nB = nzb / 64; // table row counts

    dim3 block(256);

    // --- binned path workspace: U | V | pk | ctrs ---
    const size_t U_bytes  = (size_t)nU * 64 * 2;
    const size_t V_bytes  = (size_t)nB * 64 * 2;
    const size_t pk_bytes = (size_t)nedges * 8;
    const size_t ctr_bytes = 1024 * 4;      // binCount128|binStart129|gCursor128|qCtr8
    const size_t need_binned = U_bytes + V_bytes + pk_bytes + ctr_bytes;
    const size_t need_bf16   = (size_t)nzu * 2 + (size_t)nzb * 2 + 16 * 64 * 16;

    if (ws_size >= need_binned && nU <= 131072 && nB <= 131072) {
        __hip_bfloat16* Ub = (__hip_bfloat16*)d_ws;
        __hip_bfloat16* Vb = (__hip_bfloat16*)((char*)d_ws + U_bytes);
        unsigned long long* pk = (unsigned long long*)((char*)d_ws + U_bytes + V_bytes);
        int* ctrs = (int*)((char*)d_ws + U_bytes + V_bytes + pk_bytes);
        int* binCount = ctrs;               // [0,128)
        int* binStart = ctrs + 128;         // [128,257)
        int* gCursor  = ctrs + 257;         // [257,385)
        int* qCtr     = ctrs + 8;           // alias into binCount's zeroed 136 ints
        // NOTE: qCtr occupies ctrs[8..15]? No — keep disjoint: qCtr = ctrs+385.
        qCtr = ctrs + 385;                  // zeroed below by precompute? -> scan
        // precompute_uv (zeroCtr) zeroes ctrs[0..135]; that covers binCount only.
        // scan_bins zeroes nothing extra, so zero qCtr in scan via gCursor trick:
        // simplest: precompute zeroes 512 ints — adjust: pass ctrs and rely on
        // threadIdx.x<136. Instead we zero qCtr inside scan_bins thread 0 below
        // is not implemented; so zero qCtr by making precompute zero 512:
        // (threadIdx.x<136 covers only binCount) -> use a tiny extra trick:
        // scan writes qCtr via loop in thread 0? scan_bins doesn't. Fix here:
        // launch precompute with ctrs pointer such that [0..135] covers what we
        // must zero: we need binCount[128] AND qCtr[8] = 136 ints contiguous.
        // So place qCtr immediately after binCount:
        qCtr     = ctrs + 128;              // [128,136) zeroed by precompute
        binStart = ctrs + 136;              // [136,265)
        gCursor  = ctrs + 265;              // [265,393)

        const float su = 8.0f  / (float)nU;
        const float sb = 16.0f / (float)nB;

        hipLaunchKernelGGL(precompute_uv, dim3(512), block, 0, stream,
                           zu, w1, b1, Ub, ctrs, 1, nU, 0);
        hipLaunchKernelGGL(precompute_uv, dim3(512), block, 0, stream,
                           zb, w1, (const float*)nullptr, Vb, ctrs, 0, nB, 64);
        hipLaunchKernelGGL(count_bins, dim3(1024), block, 0, stream,
                           ei, binCount, nedges, su, sb);
        hipLaunchKernelGGL(scan_bins, dim3(1), dim3(64), 0, stream,
                           binCount, binStart, gCursor);
        hipLaunchKernelGGL(scatter_bins, dim3(512), block, 0, stream,
                           ei, gCursor, pk, nedges, su, sb);
        hipLaunchKernelGGL(edge_decode_binned, dim3(2048), block, 0, stream,
                           (const uint4*)Ub, (const uint4*)Vb, pk, binStart, qCtr,
                           w2, b2, out);
    } else if (ws_size >= need_bf16) {
        uint4* zub = (uint4*)d_ws;
        uint4* zbb = (uint4*)((char*)d_ws + (size_t)nzu * 2);
        uint4* w1f = (uint4*)((char*)d_ws + (size_t)nzu * 2 + (size_t)nzb * 2);
        hipLaunchKernelGGL(cvt_bf16_pass, dim3(2048), block, 0, stream,
                           zu, zb, w1, zub, zbb, w1f, nzu / 8, nzb / 8);
        hipLaunchKernelGGL(edge_decoder_mfma_bf16, dim3(1536), block, 0, stream,
                           zub, zbb, ei, w1f, b1, w2, b2, out, nedges);
    } else {
        hipLaunchKernelGGL(edge_decoder_mfma_f32, dim3(2048), block, 0, stream,
                           zu, zb, ei, w1, b1, w2, b2, out, nedges);
    }
}

// Round 6
// 997.999 us; speedup vs baseline: 1.0978x; 1.0978x over previous
//
#include <hip/hip_runtime.h>
#include <hip/hip_bf16.h>
#include <stdint.h>
#include <string.h>

typedef __bf16 bf16x8 __attribute__((ext_vector_type(8)));
typedef float  f32x4  __attribute__((ext_vector_type(4)));

#define IDX_MASK 131071ull   // 17 bits; requires num_rows <= 131072 (100k here)

// Convert 8 consecutive fp32 (two float4s) to packed bf16x8 (RNE).
static __device__ inline bf16x8 cvt8(const float4 a, const float4 b) {
    bf16x8 r;
    r[0] = (__bf16)a.x; r[1] = (__bf16)a.y; r[2] = (__bf16)a.z; r[3] = (__bf16)a.w;
    r[4] = (__bf16)b.x; r[5] = (__bf16)b.y; r[6] = (__bf16)b.z; r[7] = (__bf16)b.w;
    return r;
}

// ============ pass 1 (x2): U = z @ W1part^T (+bias), bf16 out ============
// wave handles 16 table rows, K=64, N=64: 2 K-steps x 4 N-tiles of
// mfma_f32_16x16x32_bf16. koff selects W1 columns (0 for user, 64 for book).
// zeroCtr=1 also zeroes binCount[128]+qCtr[8] (ctrs[0..135]).
__global__ __launch_bounds__(256, 4)
void precompute_uv(const float* __restrict__ z, const float* __restrict__ w1,
                   const float* __restrict__ bias,      // may be null
                   __hip_bfloat16* __restrict__ Ub,     // [nrows][64] bf16
                   int* __restrict__ ctrs, const int zeroCtr,
                   const int nrows, const int koff)
{
    if (zeroCtr && blockIdx.x == 0 && threadIdx.x < 136)
        ctrs[threadIdx.x] = 0;

    const int lane = threadIdx.x & 63;
    const int m    = lane & 15;
    const int quad = lane >> 4;

    // B-fragments (32 VGPRs): B[t][s][j] = W1[n=t*16+m][koff+s*32+quad*8+j]
    bf16x8 Bf[4][2];
#pragma unroll
    for (int t = 0; t < 4; ++t) {
        const float* wrow = w1 + (size_t)(t * 16 + m) * 128 + koff;
#pragma unroll
        for (int s = 0; s < 2; ++s) {
            const float4* p = (const float4*)(wrow + s * 32 + quad * 8);
            Bf[t][s] = cvt8(p[0], p[1]);
        }
    }
    float bv[4];
#pragma unroll
    for (int t = 0; t < 4; ++t) bv[t] = bias ? bias[t * 16 + m] : 0.f;

    const int gwave  = (blockIdx.x * blockDim.x + threadIdx.x) >> 6;
    const int nwaves = (gridDim.x * blockDim.x) >> 6;
    const int ngroups = (nrows + 15) >> 4;

    for (int g = gwave; g < ngroups; g += nwaves) {
        const int i0 = g << 4;
        int row = i0 + m; if (row >= nrows) row = nrows - 1;
        const float* zrow = z + (size_t)row * 64;
        bf16x8 A[2];
#pragma unroll
        for (int s = 0; s < 2; ++s) {
            const float4* p = (const float4*)(zrow + s * 32 + quad * 8);
            A[s] = cvt8(p[0], p[1]);
        }
        f32x4 acc[4];
#pragma unroll
        for (int t = 0; t < 4; ++t) acc[t] = (f32x4){0.f, 0.f, 0.f, 0.f};
#pragma unroll
        for (int t = 0; t < 4; ++t) {
            acc[t] = __builtin_amdgcn_mfma_f32_16x16x32_bf16(A[0], Bf[t][0], acc[t], 0, 0, 0);
            acc[t] = __builtin_amdgcn_mfma_f32_16x16x32_bf16(A[1], Bf[t][1], acc[t], 0, 0, 0);
        }
        // C layout: reg rr = D[row=quad*4+rr][col=m] of tile t -> col t*16+m
#pragma unroll
        for (int t = 0; t < 4; ++t)
#pragma unroll
            for (int rr = 0; rr < 4; ++rr) {
                const int orow = i0 + quad * 4 + rr;
                if (orow < nrows)
                    Ub[(size_t)orow * 64 + t * 16 + m] =
                        __float2bfloat16(acc[t][rr] + bv[t]);
            }
    }
}

// ============ pass 2: per-bin histogram ============
__global__ __launch_bounds__(256)
void count_bins(const int* __restrict__ eidx, int* __restrict__ binCount,
                const int nedges, const float su, const float sb)
{
    __shared__ int h[128];
    if (threadIdx.x < 128) h[threadIdx.x] = 0;
    __syncthreads();
    const int stride = gridDim.x * blockDim.x;
    for (int e = blockIdx.x * blockDim.x + threadIdx.x; e < nedges; e += stride) {
        const int r = eidx[e], c = eidx[nedges + e];
        int ub = (int)((float)r * su); if (ub > 7)  ub = 7;
        int vb = (int)((float)c * sb); if (vb > 15) vb = 15;
        atomicAdd(&h[ub * 16 + vb], 1);
    }
    __syncthreads();
    if (threadIdx.x < 128 && h[threadIdx.x])
        atomicAdd(&binCount[threadIdx.x], h[threadIdx.x]);
}

// ============ pass 3: parallel scan, 1 block x 128 threads ============
// (R5's serial 1-thread scan = ~128 dependent global round-trips ~20us.)
__global__ void scan_bins(const int* __restrict__ binCount,
                          int* __restrict__ binStart, int* __restrict__ gCursor)
{
    __shared__ int tmp[128];
    const int t = threadIdx.x;           // exactly 128 threads
    const int v = binCount[t];
    tmp[t] = v;
    __syncthreads();
    for (int off = 1; off < 128; off <<= 1) {
        const int x = (t >= off) ? tmp[t - off] : 0;
        __syncthreads();
        tmp[t] += x;
        __syncthreads();
    }
    const int excl = tmp[t] - v;         // exclusive prefix
    binStart[t] = excl;
    gCursor[t]  = excl;
    if (t == 127) binStart[128] = tmp[127];
}

// ============ pass 4: scatter edges into bins (packed r|c|eid) ============
__global__ __launch_bounds__(256)
void scatter_bins(const int* __restrict__ eidx, int* __restrict__ gCursor,
                  unsigned long long* __restrict__ pk,
                  const int nedges, const float su, const float sb)
{
    __shared__ int h[128];
    const int chunk = (nedges + gridDim.x - 1) / gridDim.x;
    const int lo = blockIdx.x * chunk;
    const int hi = min(lo + chunk, nedges);

    if (threadIdx.x < 128) h[threadIdx.x] = 0;
    __syncthreads();
    for (int e = lo + threadIdx.x; e < hi; e += blockDim.x) {
        const int r = eidx[e], c = eidx[nedges + e];
        int ub = (int)((float)r * su); if (ub > 7)  ub = 7;
        int vb = (int)((float)c * sb); if (vb > 15) vb = 15;
        atomicAdd(&h[ub * 16 + vb], 1);
    }
    __syncthreads();
    int base = 0, cnt = 0;
    if (threadIdx.x < 128) {
        cnt = h[threadIdx.x];
        if (cnt) base = atomicAdd(&gCursor[threadIdx.x], cnt);
    }
    __syncthreads();
    if (threadIdx.x < 128) h[threadIdx.x] = base;
    __syncthreads();
    for (int e = lo + threadIdx.x; e < hi; e += blockDim.x) {
        const int r = eidx[e], c = eidx[nedges + e];
        int ub = (int)((float)r * su); if (ub > 7)  ub = 7;
        int vb = (int)((float)c * sb); if (vb > 15) vb = 15;
        const int slot = atomicAdd(&h[ub * 16 + vb], 1);
        pk[slot] = (unsigned long long)(unsigned)r
                 | ((unsigned long long)(unsigned)c << 17)
                 | ((unsigned long long)(unsigned)e  << 34);
    }
}

// ============ pass 5: binned edge decode — COOPERATIVE gather layout ======
// R5's per-lane-per-edge layout made every VMEM instruction touch 64 distinct
// 128B rows -> address-divergence serialization (930us, VALUBusy 2%). Now a
// wave does 16 edges/iter with lane=(m,quad): lane loads U[r_m] chunks
// {quad,quad+4} and V[c_m] chunks {quad,quad+4} -> 16 distinct 64B segments
// per instruction (R4's empirically-fast pattern). Per-lane partial dot over
// its 16 k-positions, quad-reduce via shfl_xor(16,32), quad0 stores.
// XCD-local queue first (s_getreg HW_REG_XCC_ID), then steal others.
__global__ __launch_bounds__(256, 4)
void edge_decode_binned(const uint4* __restrict__ Ub, const uint4* __restrict__ Vb,
                        const unsigned long long* __restrict__ pk,
                        const int* __restrict__ binStart, int* __restrict__ qCtr,
                        const float* __restrict__ w2, const float* __restrict__ b2,
                        float* __restrict__ out)
{
    const int lane = threadIdx.x & 63;
    const int m    = lane & 15;
    const int quad = lane >> 4;

    // Lane's W2 slice: chunks quad (k=quad*8+j) and quad+4 (k=32+quad*8+j).
    float w2a[8], w2b[8];
#pragma unroll
    for (int j = 0; j < 8; ++j) {
        w2a[j] = w2[quad * 8 + j];
        w2b[j] = w2[32 + quad * 8 + j];
    }
    const float b2f = b2[0];

    const int xcd = __builtin_amdgcn_s_getreg((3 << 11) | (0 << 6) | 20) & 7;

    for (int q = 0; q < 8; ++q) {
        const int qq  = (xcd + q) & 7;
        const int lo  = binStart[qq * 16];
        const int len = binStart[qq * 16 + 16] - lo;
        if (len <= 0) continue;
        while (true) {
            int t0 = 0;
            if (lane == 0) t0 = atomicAdd(&qCtr[qq], 1024);
            t0 = __shfl(t0, 0, 64);
            if (t0 >= len) break;
            const int iend = min(t0 + 1024, len);
            for (int i0 = t0; i0 < iend; i0 += 16) {
                const bool valid = (i0 + m) < len;
                const int  ec = lo + (valid ? i0 + m : len - 1);
                const unsigned long long v = pk[ec];
                const int r  = (int)(v & IDX_MASK);
                const int c  = (int)((v >> 17) & IDX_MASK);
                const int id = (int)(v >> 34);
                const uint4* up = Ub + (size_t)r * 8;
                const uint4* vp = Vb + (size_t)c * 8;
                const bf16x8 u0 = __builtin_bit_cast(bf16x8, up[quad]);
                const bf16x8 u1 = __builtin_bit_cast(bf16x8, up[quad + 4]);
                const bf16x8 v0 = __builtin_bit_cast(bf16x8, vp[quad]);
                const bf16x8 v1 = __builtin_bit_cast(bf16x8, vp[quad + 4]);
                float p = 0.f;
#pragma unroll
                for (int j = 0; j < 8; ++j) {
                    p = fmaf(fmaxf((float)u0[j] + (float)v0[j], 0.f), w2a[j], p);
                    p = fmaf(fmaxf((float)u1[j] + (float)v1[j], 0.f), w2b[j], p);
                }
                p += __shfl_xor(p, 16, 64);
                p += __shfl_xor(p, 32, 64);
                if (quad == 0 && valid) out[id] = p + b2f;
            }
        }
    }
}

// ================= fallback A (R4): bf16 gather + MFMA, W1 in LDS =========
__global__ __launch_bounds__(256)
void cvt_bf16_pass(const float* __restrict__ zu, const float* __restrict__ zb,
                   const float* __restrict__ w1,
                   uint4* __restrict__ zub, uint4* __restrict__ zbb,
                   uint4* __restrict__ w1f,
                   const int ngu, const int ngb)
{
    const int stride = gridDim.x * blockDim.x;
    const int tid = blockIdx.x * blockDim.x + threadIdx.x;
    for (int i = tid; i < ngu; i += stride) {
        const float4* s = (const float4*)zu + 2 * (size_t)i;
        zub[i] = __builtin_bit_cast(uint4, cvt8(s[0], s[1]));
    }
    for (int i = tid; i < ngb; i += stride) {
        const float4* s = (const float4*)zb + 2 * (size_t)i;
        zbb[i] = __builtin_bit_cast(uint4, cvt8(s[0], s[1]));
    }
    if (tid < 1024) {
        const int fid = tid >> 6, lane = tid & 63;
        const int t = fid >> 2, s = fid & 3;
        const int n  = t * 16 + (lane & 15);
        const int k0 = s * 32 + (lane >> 4) * 8;
        const float4* src = (const float4*)(w1 + (size_t)n * 128 + k0);
        w1f[tid] = __builtin_bit_cast(uint4, cvt8(src[0], src[1]));
    }
}

__global__ __launch_bounds__(256, 6)
void edge_decoder_mfma_bf16(const uint4* __restrict__ zub, const uint4* __restrict__ zbb,
                            const int* __restrict__ eidx, const uint4* __restrict__ w1f,
                            const float* __restrict__ b1, const float* __restrict__ w2,
                            const float* __restrict__ b2, float* __restrict__ out,
                            const int nedges)
{
    __shared__ uint4 w1lds[16 * 64];
    const int lane = threadIdx.x & 63;
    const int m = lane & 15, quad = lane >> 4;
#pragma unroll
    for (int i = 0; i < 4; ++i)
        w1lds[i * 256 + threadIdx.x] = w1f[i * 256 + threadIdx.x];
    __syncthreads();
    float w2v[4], b1v[4];
#pragma unroll
    for (int t = 0; t < 4; ++t) { w2v[t] = w2[t * 16 + m]; b1v[t] = b1[t * 16 + m]; }
    const float b2f = b2[0];
    const int wavesPerBlock = blockDim.x >> 6;
    const int gwave  = blockIdx.x * wavesPerBlock + (threadIdx.x >> 6);
    const int nwaves = gridDim.x * wavesPerBlock;
    const int* rowp = eidx; const int* colp = eidx + nedges;
    const int ngroups = (nedges + 15) >> 4;
    const uint4* lfrag = w1lds + lane;
    for (int g = gwave; g < ngroups; g += nwaves) {
        const int ebase = g << 4;
        int e = ebase + m; if (e >= nedges) e = nedges - 1;
        const int r = rowp[e], c = colp[e];
        const uint4* up = zub + (size_t)r * 8;
        const uint4* vp = zbb + (size_t)c * 8;
        bf16x8 A[4];
        A[0] = __builtin_bit_cast(bf16x8, up[quad]);
        A[1] = __builtin_bit_cast(bf16x8, up[quad + 4]);
        A[2] = __builtin_bit_cast(bf16x8, vp[quad]);
        A[3] = __builtin_bit_cast(bf16x8, vp[quad + 4]);
        f32x4 acc[4];
#pragma unroll
        for (int t = 0; t < 4; ++t) acc[t] = (f32x4){0.f, 0.f, 0.f, 0.f};
#pragma unroll
        for (int t = 0; t < 4; ++t)
#pragma unroll
            for (int s = 0; s < 4; ++s) {
                bf16x8 B = __builtin_bit_cast(bf16x8, lfrag[(t * 4 + s) * 64]);
                acc[t] = __builtin_amdgcn_mfma_f32_16x16x32_bf16(A[s], B, acc[t], 0, 0, 0);
            }
        float p[4] = {0.f, 0.f, 0.f, 0.f};
#pragma unroll
        for (int t = 0; t < 4; ++t)
#pragma unroll
            for (int rr = 0; rr < 4; ++rr) {
                float h = fmaxf(acc[t][rr] + b1v[t], 0.f);
                p[rr] = fmaf(h, w2v[t], p[rr]);
            }
#pragma unroll
        for (int off = 8; off >= 1; off >>= 1)
#pragma unroll
            for (int rr = 0; rr < 4; ++rr) p[rr] += __shfl_xor(p[rr], off, 64);
        if (m == 0) {
            const int eo = ebase + quad * 4;
            if (eo + 3 < nedges) {
                float4 o; o.x = p[0] + b2f; o.y = p[1] + b2f;
                o.z = p[2] + b2f; o.w = p[3] + b2f;
                *(float4*)(out + eo) = o;
            } else {
#pragma unroll
                for (int rr = 0; rr < 4; ++rr)
                    if (eo + rr < nedges) out[eo + rr] = p[rr] + b2f;
            }
        }
    }
}

// ================= fallback B: direct fp32 gather (no workspace) ==========
__global__ __launch_bounds__(256, 4)
void edge_decoder_mfma_f32(const float* __restrict__ zu, const float* __restrict__ zb,
                           const int* __restrict__ eidx, const float* __restrict__ w1,
                           const float* __restrict__ b1, const float* __restrict__ w2,
                           const float* __restrict__ b2, float* __restrict__ out,
                           const int nedges)
{
    const int lane = threadIdx.x & 63;
    const int m = lane & 15, quad = lane >> 4;
    const int wavesPerBlock = blockDim.x >> 6;
    const int gwave  = blockIdx.x * wavesPerBlock + (threadIdx.x >> 6);
    const int nwaves = gridDim.x * wavesPerBlock;
    bf16x8 Bf[4][4];
#pragma unroll
    for (int t = 0; t < 4; ++t) {
        const float4* wrow = (const float4*)(w1 + (size_t)(t * 16 + m) * 128);
#pragma unroll
        for (int s = 0; s < 4; ++s) {
            const int c0 = s * 8 + quad * 2;
            Bf[t][s] = cvt8(wrow[c0], wrow[c0 + 1]);
        }
    }
    float w2v[4], b1v[4];
#pragma unroll
    for (int t = 0; t < 4; ++t) { w2v[t] = w2[t * 16 + m]; b1v[t] = b1[t * 16 + m]; }
    const float b2f = b2[0];
    const int* rowp = eidx; const int* colp = eidx + nedges;
    const int ngroups = (nedges + 15) >> 4;
    for (int g = gwave; g < ngroups; g += nwaves) {
        const int ebase = g << 4;
        int e = ebase + m; if (e >= nedges) e = nedges - 1;
        const int r = rowp[e], c = colp[e];
        const float4* up = (const float4*)(zu + (size_t)r * 64);
        const float4* vp = (const float4*)(zb + (size_t)c * 64);
        bf16x8 A0 = cvt8(up[quad * 2],     up[quad * 2 + 1]);
        bf16x8 A1 = cvt8(up[8 + quad * 2], up[9 + quad * 2]);
        bf16x8 A2 = cvt8(vp[quad * 2],     vp[quad * 2 + 1]);
        bf16x8 A3 = cvt8(vp[8 + quad * 2], vp[9 + quad * 2]);
        f32x4 acc[4];
#pragma unroll
        for (int t = 0; t < 4; ++t) acc[t] = (f32x4){0.f, 0.f, 0.f, 0.f};
#pragma unroll
        for (int t = 0; t < 4; ++t) {
            acc[t] = __builtin_amdgcn_mfma_f32_16x16x32_bf16(A0, Bf[t][0], acc[t], 0, 0, 0);
            acc[t] = __builtin_amdgcn_mfma_f32_16x16x32_bf16(A1, Bf[t][1], acc[t], 0, 0, 0);
            acc[t] = __builtin_amdgcn_mfma_f32_16x16x32_bf16(A2, Bf[t][2], acc[t], 0, 0, 0);
            acc[t] = __builtin_amdgcn_mfma_f32_16x16x32_bf16(A3, Bf[t][3], acc[t], 0, 0, 0);
        }
        float p[4] = {0.f, 0.f, 0.f, 0.f};
#pragma unroll
        for (int t = 0; t < 4; ++t)
#pragma unroll
            for (int rr = 0; rr < 4; ++rr) {
                float h = fmaxf(acc[t][rr] + b1v[t], 0.f);
                p[rr] = fmaf(h, w2v[t], p[rr]);
            }
#pragma unroll
        for (int off = 8; off >= 1; off >>= 1)
#pragma unroll
            for (int rr = 0; rr < 4; ++rr) p[rr] += __shfl_xor(p[rr], off, 64);
        if (m == 0) {
            const int eo = ebase + quad * 4;
            if (eo + 3 < nedges) {
                float4 o; o.x = p[0] + b2f; o.y = p[1] + b2f;
                o.z = p[2] + b2f; o.w = p[3] + b2f;
                *(float4*)(out + eo) = o;
            } else {
#pragma unroll
                for (int rr = 0; rr < 4; ++rr)
                    if (eo + rr < nedges) out[eo + rr] = p[rr] + b2f;
            }
        }
    }
}

extern "C" void kernel_launch(void* const* d_in, const int* in_sizes, int n_in,
                              void* d_out, int out_size, void* d_ws, size_t ws_size,
                              hipStream_t stream) {
    const float* zu = (const float*)d_in[0];
    const float* zb = (const float*)d_in[1];
    const int*   ei = (const int*)d_in[2];
    const float* w1 = (const float*)d_in[3];
    const float* b1 = (const float*)d_in[4];
    const float* w2 = (const float*)d_in[5];
    const float* b2 = (const float*)d_in[6];
    float* out = (float*)d_out;

    const int nedges = in_sizes[2] / 2;     // edge_label_index is [2, E]
    const int nzu = in_sizes[0], nzb = in_sizes[1];
    const int nU = nzu / 64, nB = nzb / 64; // table row counts

    dim3 block(256);

    // --- binned path workspace: U | V | pk | ctrs ---
    // ctrs layout: [0,128) binCount | [128,136) qCtr | [136,265) binStart(129)
    //              | [265,393) gCursor  (precompute zeroCtr zeroes [0,136))
    const size_t U_bytes  = (size_t)nU * 64 * 2;
    const size_t V_bytes  = (size_t)nB * 64 * 2;
    const size_t pk_bytes = (size_t)nedges * 8;
    const size_t ctr_bytes = 1024 * 4;
    const size_t need_binned = U_bytes + V_bytes + pk_bytes + ctr_bytes;
    const size_t need_bf16   = (size_t)nzu * 2 + (size_t)nzb * 2 + 16 * 64 * 16;

    if (ws_size >= need_binned && nU <= 131072 && nB <= 131072) {
        __hip_bfloat16* Ub = (__hip_bfloat16*)d_ws;
        __hip_bfloat16* Vb = (__hip_bfloat16*)((char*)d_ws + U_bytes);
        unsigned long long* pk = (unsigned long long*)((char*)d_ws + U_bytes + V_bytes);
        int* ctrs = (int*)((char*)d_ws + U_bytes + V_bytes + pk_bytes);
        int* binCount = ctrs;
        int* qCtr     = ctrs + 128;
        int* binStart = ctrs + 136;
        int* gCursor  = ctrs + 265;

        const float su = 8.0f  / (float)nU;
        const float sb = 16.0f / (float)nB;

        hipLaunchKernelGGL(precompute_uv, dim3(512), block, 0, stream,
                           zu, w1, b1, Ub, ctrs, 1, nU, 0);
        hipLaunchKernelGGL(precompute_uv, dim3(512), block, 0, stream,
                           zb, w1, (const float*)nullptr, Vb, ctrs, 0, nB, 64);
        hipLaunchKernelGGL(count_bins, dim3(1024), block, 0, stream,
                           ei, binCount, nedges, su, sb);
        hipLaunchKernelGGL(scan_bins, dim3(1), dim3(128), 0, stream,
                           binCount, binStart, gCursor);
        hipLaunchKernelGGL(scatter_bins, dim3(512), block, 0, stream,
                           ei, gCursor, pk, nedges, su, sb);
        hipLaunchKernelGGL(edge_decode_binned, dim3(2048), block, 0, stream,
                           (const uint4*)Ub, (const uint4*)Vb, pk, binStart, qCtr,
                           w2, b2, out);
    } else if (ws_size >= need_bf16) {
        uint4* zub = (uint4*)d_ws;
        uint4* zbb = (uint4*)((char*)d_ws + (size_t)nzu * 2);
        uint4* w1f = (uint4*)((char*)d_ws + (size_t)nzu * 2 + (size_t)nzb * 2);
        hipLaunchKernelGGL(cvt_bf16_pass, dim3(2048), block, 0, stream,
                           zu, zb, w1, zub, zbb, w1f, nzu / 8, nzb / 8);
        hipLaunchKernelGGL(edge_decoder_mfma_bf16, dim3(1536), block, 0, stream,
                           zub, zbb, ei, w1f, b1, w2, b2, out, nedges);
    } else {
        hipLaunchKernelGGL(edge_decoder_mfma_f32, dim3(2048), block, 0, stream,
                           zu, zb, ei, w1, b1, w2, b2, out, nedges);
    }
}

// Round 7
// 369.841 us; speedup vs baseline: 2.9622x; 2.6985x over previous
//
#include <hip/hip_runtime.h>
#include <hip/hip_bf16.h>
#include <stdint.h>
#include <string.h>

typedef __bf16 bf16x8 __attribute__((ext_vector_type(8)));
typedef float  f32x4  __attribute__((ext_vector_type(4)));

#define IDX_MASK 131071ull   // 17 bits; requires num_rows <= 131072 (100k here)
#define CHUNK 128            // edges per work-steal grab (8 groups of 16)

// Convert 8 consecutive fp32 (two float4s) to packed bf16x8 (RNE).
static __device__ inline bf16x8 cvt8(const float4 a, const float4 b) {
    bf16x8 r;
    r[0] = (__bf16)a.x; r[1] = (__bf16)a.y; r[2] = (__bf16)a.z; r[3] = (__bf16)a.w;
    r[4] = (__bf16)b.x; r[5] = (__bf16)b.y; r[6] = (__bf16)b.z; r[7] = (__bf16)b.w;
    return r;
}

// ---- precompute body: Ub[nrows][64] = bf16( z @ W1part^T + bias ) ----
// wave = 16 rows, K=64, N=64: 2 K-steps x 4 N-tiles of mfma_f32_16x16x32_bf16.
static __device__ inline void precompute_body(
    const float* __restrict__ z, const float* __restrict__ w1,
    const float* __restrict__ bias, __hip_bfloat16* __restrict__ Ub,
    const int nrows, const int koff, const int blkLocal, const int nBlk)
{
    const int lane = threadIdx.x & 63;
    const int m    = lane & 15;
    const int quad = lane >> 4;

    bf16x8 Bf[4][2];
#pragma unroll
    for (int t = 0; t < 4; ++t) {
        const float* wrow = w1 + (size_t)(t * 16 + m) * 128 + koff;
#pragma unroll
        for (int s = 0; s < 2; ++s) {
            const float4* p = (const float4*)(wrow + s * 32 + quad * 8);
            Bf[t][s] = cvt8(p[0], p[1]);
        }
    }
    float bv[4];
#pragma unroll
    for (int t = 0; t < 4; ++t) bv[t] = bias ? bias[t * 16 + m] : 0.f;

    const int gwave  = (blkLocal * 256 + (int)threadIdx.x) >> 6;
    const int nwaves = nBlk * 4;
    const int ngroups = (nrows + 15) >> 4;

    for (int g = gwave; g < ngroups; g += nwaves) {
        const int i0 = g << 4;
        int row = i0 + m; if (row >= nrows) row = nrows - 1;
        const float* zrow = z + (size_t)row * 64;
        bf16x8 A[2];
#pragma unroll
        for (int s = 0; s < 2; ++s) {
            const float4* p = (const float4*)(zrow + s * 32 + quad * 8);
            A[s] = cvt8(p[0], p[1]);
        }
        f32x4 acc[4];
#pragma unroll
        for (int t = 0; t < 4; ++t) acc[t] = (f32x4){0.f, 0.f, 0.f, 0.f};
#pragma unroll
        for (int t = 0; t < 4; ++t) {
            acc[t] = __builtin_amdgcn_mfma_f32_16x16x32_bf16(A[0], Bf[t][0], acc[t], 0, 0, 0);
            acc[t] = __builtin_amdgcn_mfma_f32_16x16x32_bf16(A[1], Bf[t][1], acc[t], 0, 0, 0);
        }
        // C layout: reg rr = D[row=quad*4+rr][col=m] of tile t -> col t*16+m
#pragma unroll
        for (int t = 0; t < 4; ++t)
#pragma unroll
            for (int rr = 0; rr < 4; ++rr) {
                const int orow = i0 + quad * 4 + rr;
                if (orow < nrows)
                    Ub[(size_t)orow * 64 + t * 16 + m] =
                        __float2bfloat16(acc[t][rr] + bv[t]);
            }
    }
}

// ============ fused pass: precompute U | precompute V | count bins ========
// Disjoint block ranges, no inter-dependency (count only reads eidx).
// ctrs must be pre-zeroed (hipMemsetAsync before this launch).
__global__ __launch_bounds__(256, 4)
void fused_pre(const float* __restrict__ zu, const float* __restrict__ zb,
               const float* __restrict__ w1, const float* __restrict__ b1,
               __hip_bfloat16* __restrict__ Ub, __hip_bfloat16* __restrict__ Vb,
               const int* __restrict__ eidx, int* __restrict__ binCount,
               const int nU, const int nB, const int nedges,
               const float su, const float sb,
               const int nPreU, const int nPreV, const int nCnt)
{
    const int b = blockIdx.x;
    if (b < nPreU) {
        precompute_body(zu, w1, b1, Ub, nU, 0, b, nPreU);
    } else if (b < nPreU + nPreV) {
        precompute_body(zb, w1, nullptr, Vb, nB, 64, b - nPreU, nPreV);
    } else {
        // count bins: LDS histogram then one global atomic per bin per block
        __shared__ int h[128];
        if (threadIdx.x < 128) h[threadIdx.x] = 0;
        __syncthreads();
        const int bl = b - nPreU - nPreV;
        const int stride = nCnt * 256;
        for (int e = bl * 256 + threadIdx.x; e < nedges; e += stride) {
            const int r = eidx[e], c = eidx[nedges + e];
            int ub = (int)((float)r * su); if (ub > 7)  ub = 7;
            int vb = (int)((float)c * sb); if (vb > 15) vb = 15;
            atomicAdd(&h[ub * 16 + vb], 1);
        }
        __syncthreads();
        if (threadIdx.x < 128 && h[threadIdx.x])
            atomicAdd(&binCount[threadIdx.x], h[threadIdx.x]);
    }
}

// ============ scan: 1 block x 128 threads, LDS Hillis-Steele ============
__global__ void scan_bins(const int* __restrict__ binCount,
                          int* __restrict__ binStart, int* __restrict__ gCursor)
{
    __shared__ int tmp[128];
    const int t = threadIdx.x;           // exactly 128 threads
    const int v = binCount[t];
    tmp[t] = v;
    __syncthreads();
    for (int off = 1; off < 128; off <<= 1) {
        const int x = (t >= off) ? tmp[t - off] : 0;
        __syncthreads();
        tmp[t] += x;
        __syncthreads();
    }
    const int excl = tmp[t] - v;         // exclusive prefix
    binStart[t] = excl;
    gCursor[t]  = excl;
    if (t == 127) binStart[128] = tmp[127];
}

// ============ scatter edges into bins (packed r|c|eid) ============
__global__ __launch_bounds__(256)
void scatter_bins(const int* __restrict__ eidx, int* __restrict__ gCursor,
                  unsigned long long* __restrict__ pk,
                  const int nedges, const float su, const float sb)
{
    __shared__ int h[128];
    const int chunk = (nedges + gridDim.x - 1) / gridDim.x;
    const int lo = blockIdx.x * chunk;
    const int hi = min(lo + chunk, nedges);

    if (threadIdx.x < 128) h[threadIdx.x] = 0;
    __syncthreads();
    for (int e = lo + threadIdx.x; e < hi; e += blockDim.x) {
        const int r = eidx[e], c = eidx[nedges + e];
        int ub = (int)((float)r * su); if (ub > 7)  ub = 7;
        int vb = (int)((float)c * sb); if (vb > 15) vb = 15;
        atomicAdd(&h[ub * 16 + vb], 1);
    }
    __syncthreads();
    int base = 0, cnt = 0;
    if (threadIdx.x < 128) {
        cnt = h[threadIdx.x];
        if (cnt) base = atomicAdd(&gCursor[threadIdx.x], cnt);
    }
    __syncthreads();
    if (threadIdx.x < 128) h[threadIdx.x] = base;
    __syncthreads();
    for (int e = lo + threadIdx.x; e < hi; e += blockDim.x) {
        const int r = eidx[e], c = eidx[nedges + e];
        int ub = (int)((float)r * su); if (ub > 7)  ub = 7;
        int vb = (int)((float)c * sb); if (vb > 15) vb = 15;
        const int slot = atomicAdd(&h[ub * 16 + vb], 1);
        pk[slot] = (unsigned long long)(unsigned)r
                 | ((unsigned long long)(unsigned)c << 17)
                 | ((unsigned long long)(unsigned)e  << 34);
    }
}

// ============ binned edge decode ============
// R6 failure mode: chunk=1024 -> only 1953 chunks for 8192 waves (24% wave
// utilization, 64-deep serial chains) + all 8 qCtr on ONE cache line. Fix:
// CHUNK=128 (15.6k chunks, every wave busy), qCtr padded 128B apart, relaxed
// pre-check before the atomic (monotone counter: stale-low = one extra
// atomic; >=len can never be observed early). Gather layout stays the
// cooperative (m,quad) pattern. XCD-local queue first (s_getreg XCC_ID).
__global__ __launch_bounds__(256, 4)
void edge_decode_binned(const uint4* __restrict__ Ub, const uint4* __restrict__ Vb,
                        const unsigned long long* __restrict__ pk,
                        const int* __restrict__ binStart, int* __restrict__ qCtr,
                        const float* __restrict__ w2, const float* __restrict__ b2,
                        float* __restrict__ out)
{
    const int lane = threadIdx.x & 63;
    const int m    = lane & 15;
    const int quad = lane >> 4;

    // Lane's W2 slice: k = quad*8+j and k = 32+quad*8+j.
    float w2a[8], w2b[8];
#pragma unroll
    for (int j = 0; j < 8; ++j) {
        w2a[j] = w2[quad * 8 + j];
        w2b[j] = w2[32 + quad * 8 + j];
    }
    const float b2f = b2[0];

    const int xcd = __builtin_amdgcn_s_getreg((3 << 11) | (0 << 6) | 20) & 7;

    for (int q = 0; q < 8; ++q) {
        const int qq  = (xcd + q) & 7;
        const int lo  = binStart[qq * 16];
        const int len = binStart[qq * 16 + 16] - lo;
        if (len <= 0) continue;
        volatile int* qc = qCtr + qq * 32;   // 128B-padded counter
        while (true) {
            int t0 = 0;
            if (lane == 0) {
                const int cur = *qc;         // relaxed pre-check, no atomic
                t0 = (cur < len) ? atomicAdd((int*)qc, CHUNK) : cur;
            }
            t0 = __shfl(t0, 0, 64);
            if (t0 >= len) break;
#pragma unroll 4
            for (int it = 0; it < CHUNK / 16; ++it) {
                const int i0 = t0 + it * 16;
                const bool valid = (i0 + m) < len;
                const int  ec = lo + (valid ? i0 + m : len - 1);
                const unsigned long long v = pk[ec];
                const int r  = (int)(v & IDX_MASK);
                const int c  = (int)((v >> 17) & IDX_MASK);
                const int id = (int)(v >> 34);
                const uint4* up = Ub + (size_t)r * 8;
                const uint4* vp = Vb + (size_t)c * 8;
                const bf16x8 u0 = __builtin_bit_cast(bf16x8, up[quad]);
                const bf16x8 u1 = __builtin_bit_cast(bf16x8, up[quad + 4]);
                const bf16x8 v0 = __builtin_bit_cast(bf16x8, vp[quad]);
                const bf16x8 v1 = __builtin_bit_cast(bf16x8, vp[quad + 4]);
                float p = 0.f;
#pragma unroll
                for (int j = 0; j < 8; ++j) {
                    p = fmaf(fmaxf((float)u0[j] + (float)v0[j], 0.f), w2a[j], p);
                    p = fmaf(fmaxf((float)u1[j] + (float)v1[j], 0.f), w2b[j], p);
                }
                p += __shfl_xor(p, 16, 64);
                p += __shfl_xor(p, 32, 64);
                if (quad == 0 && valid) out[id] = p + b2f;
            }
        }
    }
}

// ================= fallback: direct fp32 gather (no workspace) ==========
__global__ __launch_bounds__(256, 4)
void edge_decoder_mfma_f32(const float* __restrict__ zu, const float* __restrict__ zb,
                           const int* __restrict__ eidx, const float* __restrict__ w1,
                           const float* __restrict__ b1, const float* __restrict__ w2,
                           const float* __restrict__ b2, float* __restrict__ out,
                           const int nedges)
{
    const int lane = threadIdx.x & 63;
    const int m = lane & 15, quad = lane >> 4;
    const int wavesPerBlock = blockDim.x >> 6;
    const int gwave  = blockIdx.x * wavesPerBlock + (threadIdx.x >> 6);
    const int nwaves = gridDim.x * wavesPerBlock;
    bf16x8 Bf[4][4];
#pragma unroll
    for (int t = 0; t < 4; ++t) {
        const float4* wrow = (const float4*)(w1 + (size_t)(t * 16 + m) * 128);
#pragma unroll
        for (int s = 0; s < 4; ++s) {
            const int c0 = s * 8 + quad * 2;
            Bf[t][s] = cvt8(wrow[c0], wrow[c0 + 1]);
        }
    }
    float w2v[4], b1v[4];
#pragma unroll
    for (int t = 0; t < 4; ++t) { w2v[t] = w2[t * 16 + m]; b1v[t] = b1[t * 16 + m]; }
    const float b2f = b2[0];
    const int* rowp = eidx; const int* colp = eidx + nedges;
    const int ngroups = (nedges + 15) >> 4;
    for (int g = gwave; g < ngroups; g += nwaves) {
        const int ebase = g << 4;
        int e = ebase + m; if (e >= nedges) e = nedges - 1;
        const int r = rowp[e], c = colp[e];
        const float4* up = (const float4*)(zu + (size_t)r * 64);
        const float4* vp = (const float4*)(zb + (size_t)c * 64);
        bf16x8 A0 = cvt8(up[quad * 2],     up[quad * 2 + 1]);
        bf16x8 A1 = cvt8(up[8 + quad * 2], up[9 + quad * 2]);
        bf16x8 A2 = cvt8(vp[quad * 2],     vp[quad * 2 + 1]);
        bf16x8 A3 = cvt8(vp[8 + quad * 2], vp[9 + quad * 2]);
        f32x4 acc[4];
#pragma unroll
        for (int t = 0; t < 4; ++t) acc[t] = (f32x4){0.f, 0.f, 0.f, 0.f};
#pragma unroll
        for (int t = 0; t < 4; ++t) {
            acc[t] = __builtin_amdgcn_mfma_f32_16x16x32_bf16(A0, Bf[t][0], acc[t], 0, 0, 0);
            acc[t] = __builtin_amdgcn_mfma_f32_16x16x32_bf16(A1, Bf[t][1], acc[t], 0, 0, 0);
            acc[t] = __builtin_amdgcn_mfma_f32_16x16x32_bf16(A2, Bf[t][2], acc[t], 0, 0, 0);
            acc[t] = __builtin_amdgcn_mfma_f32_16x16x32_bf16(A3, Bf[t][3], acc[t], 0, 0, 0);
        }
        float p[4] = {0.f, 0.f, 0.f, 0.f};
#pragma unroll
        for (int t = 0; t < 4; ++t)
#pragma unroll
            for (int rr = 0; rr < 4; ++rr) {
                float h = fmaxf(acc[t][rr] + b1v[t], 0.f);
                p[rr] = fmaf(h, w2v[t], p[rr]);
            }
#pragma unroll
        for (int off = 8; off >= 1; off >>= 1)
#pragma unroll
            for (int rr = 0; rr < 4; ++rr) p[rr] += __shfl_xor(p[rr], off, 64);
        if (m == 0) {
            const int eo = ebase + quad * 4;
            if (eo + 3 < nedges) {
                float4 o; o.x = p[0] + b2f; o.y = p[1] + b2f;
                o.z = p[2] + b2f; o.w = p[3] + b2f;
                *(float4*)(out + eo) = o;
            } else {
#pragma unroll
                for (int rr = 0; rr < 4; ++rr)
                    if (eo + rr < nedges) out[eo + rr] = p[rr] + b2f;
            }
        }
    }
}

extern "C" void kernel_launch(void* const* d_in, const int* in_sizes, int n_in,
                              void* d_out, int out_size, void* d_ws, size_t ws_size,
                              hipStream_t stream) {
    const float* zu = (const float*)d_in[0];
    const float* zb = (const float*)d_in[1];
    const int*   ei = (const int*)d_in[2];
    const float* w1 = (const float*)d_in[3];
    const float* b1 = (const float*)d_in[4];
    const float* w2 = (const float*)d_in[5];
    const float* b2 = (const float*)d_in[6];
    float* out = (float*)d_out;

    const int nedges = in_sizes[2] / 2;     // edge_label_index is [2, E]
    const int nzu = in_sizes[0], nzb = in_sizes[1];
    const int nU = nzu / 64, nB = nzb / 64; // table row counts

    dim3 block(256);

    // --- workspace: U | V | pk | ctrs(4KB) ---
    // ctrs ints: [0,128) binCount | [128,257) binStart | [257,385) gCursor
    //            | [512,768) qCtr padded (stride 32 ints = 128B)
    const size_t U_bytes  = (size_t)nU * 64 * 2;
    const size_t V_bytes  = (size_t)nB * 64 * 2;
    const size_t pk_bytes = (size_t)nedges * 8;
    const size_t ctr_bytes = 1024 * 4;
    const size_t need_binned = U_bytes + V_bytes + pk_bytes + ctr_bytes;

    if (ws_size >= need_binned && nU <= 131072 && nB <= 131072 && nU > 0 && nB > 0) {
        __hip_bfloat16* Ub = (__hip_bfloat16*)d_ws;
        __hip_bfloat16* Vb = (__hip_bfloat16*)((char*)d_ws + U_bytes);
        unsigned long long* pk = (unsigned long long*)((char*)d_ws + U_bytes + V_bytes);
        int* ctrs = (int*)((char*)d_ws + U_bytes + V_bytes + pk_bytes);
        int* binCount = ctrs;
        int* binStart = ctrs + 128;
        int* gCursor  = ctrs + 257;
        int* qCtr     = ctrs + 512;

        const float su = 8.0f  / (float)nU;
        const float sb = 16.0f / (float)nB;

        const int nPreU = 384, nPreV = 384, nCnt = 256;  // fused grid = 1024

        hipMemsetAsync(ctrs, 0, ctr_bytes, stream);      // capture-safe
        hipLaunchKernelGGL(fused_pre, dim3(nPreU + nPreV + nCnt), block, 0, stream,
                           zu, zb, w1, b1, Ub, Vb, ei, binCount,
                           nU, nB, nedges, su, sb, nPreU, nPreV, nCnt);
        hipLaunchKernelGGL(scan_bins, dim3(1), dim3(128), 0, stream,
                           binCount, binStart, gCursor);
        hipLaunchKernelGGL(scatter_bins, dim3(1024), block, 0, stream,
                           ei, gCursor, pk, nedges, su, sb);
        hipLaunchKernelGGL(edge_decode_binned, dim3(2048), block, 0, stream,
                           (const uint4*)Ub, (const uint4*)Vb, pk, binStart, qCtr,
                           w2, b2, out);
    } else {
        hipLaunchKernelGGL(edge_decoder_mfma_f32, dim3(2048), block, 0, stream,
                           zu, zb, ei, w1, b1, w2, b2, out, nedges);
    }
}